// Round 1
// baseline (405.588 us; speedup 1.0000x reference)
//
#include <hip/hip_runtime.h>
#include <cstdint>

#define BB 256
#define DD 512
#define CC 345
#define NBANK 50000
#define KNEI 5
#define ALPHAC 1.0f
#define EPSN 1e-12f

#define TN 64
#define BK 64
#define LDA 72
#define LDB 72

typedef short short8 __attribute__((ext_vector_type(8)));
typedef float f32x4 __attribute__((ext_vector_type(4)));

__device__ inline uint32_t f2bf1(float x) {
    union { float f; uint32_t u; } v; v.f = x;
    return (v.u + 0x7FFFu + ((v.u >> 16) & 1u)) >> 16;
}

__device__ inline bool better(float v1, int i1, float v2, int i2) {
    return (v1 > v2) || (v1 == v2 && i1 < i2);
}

// Kernel 1: zero the output scalar + compute last-write-wins winner flags
__global__ void winner_kernel(const int* __restrict__ trg, int* __restrict__ win,
                              float* __restrict__ out) {
    int t = threadIdx.x;
    if (t == 0) out[0] = 0.f;
    int mv = trg[t];
    int w = 1;
    for (int b2 = t + 1; b2 < BB; b2++)
        if (trg[b2] == mv) w = 0;   // a later row writes the same bank slot
    win[t] = w;
}

// Kernel 2: row L2-normalize features -> f32 + bf16 copies
__global__ void norm_kernel(const float* __restrict__ feat, float* __restrict__ fn,
                            unsigned short* __restrict__ fnb) {
    int b = blockIdx.x, t = threadIdx.x;
    float x0 = feat[b * DD + t];
    float x1 = feat[b * DD + t + 256];
    __shared__ float red[256];
    red[t] = x0 * x0 + x1 * x1;
    __syncthreads();
    for (int s = 128; s > 0; s >>= 1) {
        if (t < s) red[t] += red[t + s];
        __syncthreads();
    }
    float inv = 1.0f / fmaxf(sqrtf(red[0]), EPSN);
    float y0 = x0 * inv, y1 = x1 * inv;
    fn[b * DD + t] = y0;
    fn[b * DD + t + 256] = y1;
    fnb[b * DD + t] = (unsigned short)f2bf1(y0);
    fnb[b * DD + t + 256] = (unsigned short)f2bf1(y1);
}

// Kernel 3: row softmax of predictions
__global__ void softmax_kernel(const float* __restrict__ pred, float* __restrict__ p) {
    int b = blockIdx.x, t = threadIdx.x;
    float x0 = (t < CC) ? pred[b * CC + t] : -3.0e38f;
    float x1 = (t + 256 < CC) ? pred[b * CC + t + 256] : -3.0e38f;
    __shared__ float red[256];
    red[t] = fmaxf(x0, x1);
    __syncthreads();
    for (int s = 128; s > 0; s >>= 1) {
        if (t < s) red[t] = fmaxf(red[t], red[t + s]);
        __syncthreads();
    }
    float M = red[0];
    __syncthreads();
    float e0 = (t < CC) ? expf(x0 - M) : 0.f;
    float e1 = (t + 256 < CC) ? expf(x1 - M) : 0.f;
    red[t] = e0 + e1;
    __syncthreads();
    for (int s = 128; s > 0; s >>= 1) {
        if (t < s) red[t] += red[t + s];
        __syncthreads();
    }
    float inv = 1.0f / red[0];
    if (t < CC) p[b * CC + t] = e0 * inv;
    if (t + 256 < CC) p[b * CC + t + 256] = e1 * inv;
}

// Kernel 4: distance = f_norm @ bank^T  (bf16 MFMA, fp32 acc).
// One block covers ALL 256 rows x 64 bank columns so bank is read exactly once.
__global__ __launch_bounds__(256) void gemm_kernel(const unsigned short* __restrict__ fnb,
                                                   const float* __restrict__ bank,
                                                   float* __restrict__ dist) {
    __shared__ __align__(16) unsigned short As[BB * LDA];  // 36864 B
    __shared__ __align__(16) unsigned short Bs[TN * LDB];  //  9216 B
    int t = threadIdx.x;
    int j0 = blockIdx.x * TN;
    int w = t >> 6, lane = t & 63, quad = lane >> 4, l16 = lane & 15;

    f32x4 acc[4][4];
#pragma unroll
    for (int mt = 0; mt < 4; mt++)
#pragma unroll
        for (int nt = 0; nt < 4; nt++)
            acc[mt][nt] = (f32x4){0.f, 0.f, 0.f, 0.f};

    for (int kt = 0; kt < DD / BK; kt++) {
        int k0 = kt * BK;
        // stage A: thread t copies its own row chunk (64 bf16 = 128 B)
        {
            const uint4* src = (const uint4*)(fnb + t * DD + k0);
            uint4* dst = (uint4*)(As + t * LDA);
#pragma unroll
            for (int u = 0; u < 8; u++) dst[u] = src[u];
        }
        // stage B: 4 threads per bank row, convert f32 -> bf16
        {
            int r = t >> 2, cq = t & 3;
            int j = j0 + r;
            uint32_t tmp[8];
            if (j < NBANK) {
                const f32x4* src = (const f32x4*)(bank + (size_t)j * DD + k0 + cq * 16);
#pragma unroll
                for (int u = 0; u < 4; u++) {
                    f32x4 f = src[u];
                    tmp[2 * u + 0] = f2bf1(f[0]) | (f2bf1(f[1]) << 16);
                    tmp[2 * u + 1] = f2bf1(f[2]) | (f2bf1(f[3]) << 16);
                }
            } else {
#pragma unroll
                for (int u = 0; u < 8; u++) tmp[u] = 0;
            }
            uint4* dst = (uint4*)(Bs + r * LDB + cq * 16);
            dst[0] = make_uint4(tmp[0], tmp[1], tmp[2], tmp[3]);
            dst[1] = make_uint4(tmp[4], tmp[5], tmp[6], tmp[7]);
        }
        __syncthreads();
#pragma unroll
        for (int ks = 0; ks < 2; ks++) {
            short8 af[4], bf[4];
#pragma unroll
            for (int mt = 0; mt < 4; mt++)
                af[mt] = *(const short8*)(As + (w * 64 + mt * 16 + l16) * LDA + ks * 32 + quad * 8);
#pragma unroll
            for (int nt = 0; nt < 4; nt++)
                bf[nt] = *(const short8*)(Bs + (nt * 16 + l16) * LDB + ks * 32 + quad * 8);
#pragma unroll
            for (int mt = 0; mt < 4; mt++)
#pragma unroll
                for (int nt = 0; nt < 4; nt++)
                    acc[mt][nt] = __builtin_amdgcn_mfma_f32_16x16x32_bf16(
                        af[mt], bf[nt], acc[mt][nt], 0, 0, 0);
        }
        __syncthreads();
    }
    // epilogue: D[row=quad*4+r][col=l16] per 16x16 tile
#pragma unroll
    for (int mt = 0; mt < 4; mt++)
#pragma unroll
        for (int nt = 0; nt < 4; nt++)
#pragma unroll
            for (int r = 0; r < 4; r++) {
                int i = w * 64 + mt * 16 + quad * 4 + r;
                int j = j0 + nt * 16 + l16;
                if (j < NBANK) dist[(size_t)i * NBANK + j] = acc[mt][nt][r];
            }
}

// Kernel 5: patch scattered columns in fp32 (bank rows replaced by f_norm rows)
__global__ void fixup_kernel(const float* __restrict__ fn, const int* __restrict__ trg,
                             const int* __restrict__ win, float* __restrict__ dist) {
    int b2 = blockIdx.x;
    if (!win[b2]) return;
    int j = trg[b2];
    int i = threadIdx.x;
    const f32x4* a = (const f32x4*)(fn + i * DD);
    const f32x4* c = (const f32x4*)(fn + b2 * DD);
    float dot = 0.f;
#pragma unroll 8
    for (int u = 0; u < DD / 4; u++) {
        f32x4 x = a[u], y = c[u];
        dot += x[0] * y[0] + x[1] * y[1] + x[2] * y[2] + x[3] * y[3];
    }
    dist[(size_t)i * NBANK + j] = dot;
}

// Kernel 6: per-row top-6 (value desc, tie -> smaller index), keep ranks 1..5
__global__ void topk_kernel(const float* __restrict__ dist, int* __restrict__ nidx) {
    int i = blockIdx.x, t = threadIdx.x;
    float lv[6];
    int li[6];
#pragma unroll
    for (int r = 0; r < 6; r++) { lv[r] = -3.4e38f; li[r] = 0x7FFFFFFF; }
    const float* row = dist + (size_t)i * NBANK;
    for (int j = t; j < NBANK; j += 256) {
        float v = row[j];
        if (better(v, j, lv[5], li[5])) {
            int q = 5;
            while (q > 0 && better(v, j, lv[q - 1], li[q - 1])) {
                lv[q] = lv[q - 1]; li[q] = li[q - 1]; q--;
            }
            lv[q] = v; li[q] = j;
        }
    }
    __shared__ float sv[1536];
    __shared__ int si[1536];
#pragma unroll
    for (int r = 0; r < 6; r++) { sv[t * 6 + r] = lv[r]; si[t * 6 + r] = li[r]; }
    __syncthreads();
    for (int s = 128; s > 0; s >>= 1) {
        if (t < s) {
            float av[6], bv[6], rv[6];
            int ai[6], bi[6], ri[6];
#pragma unroll
            for (int r = 0; r < 6; r++) {
                av[r] = sv[t * 6 + r];       ai[r] = si[t * 6 + r];
                bv[r] = sv[(t + s) * 6 + r]; bi[r] = si[(t + s) * 6 + r];
            }
            int x = 0, y = 0;
#pragma unroll
            for (int o = 0; o < 6; o++) {
                if (better(av[x], ai[x], bv[y], bi[y])) { rv[o] = av[x]; ri[o] = ai[x]; x++; }
                else                                    { rv[o] = bv[y]; ri[o] = bi[y]; y++; }
            }
#pragma unroll
            for (int r = 0; r < 6; r++) { sv[t * 6 + r] = rv[r]; si[t * 6 + r] = ri[r]; }
        }
        __syncthreads();
    }
    if (t == 0) {
#pragma unroll
        for (int r = 1; r < 6; r++) nidx[i * KNEI + r - 1] = si[r];
    }
}

// Kernel 7: KL term, gathering score rows with scatter patch (last-wins lookup)
__global__ void kl_kernel(const float* __restrict__ p, const float* __restrict__ sbank,
                          const int* __restrict__ nidx, const int* __restrict__ trg,
                          float* __restrict__ out) {
    int b = blockIdx.x, t = threadIdx.x;
    __shared__ int sj[KNEI], sb[KNEI];
    if (t < KNEI) {
        int j = nidx[b * KNEI + t];
        sj[t] = j;
        int src = -1;
        for (int b2 = 0; b2 < BB; b2++)
            if (trg[b2] == j) src = b2;   // last wins
        sb[t] = src;
    }
    __syncthreads();
    float local = 0.f;
    for (int k = 0; k < KNEI; k++) {
        int j = sj[k], src = sb[k];
        const float* srow = (src >= 0) ? (p + src * CC) : (sbank + (size_t)j * CC);
        for (int c = t; c < CC; c += 256) {
            float s = srow[c];
            local += s * (logf(s) - p[b * CC + c]);
        }
    }
    __shared__ float red[256];
    red[t] = local;
    __syncthreads();
    for (int s = 128; s > 0; s >>= 1) {
        if (t < s) red[t] += red[t + s];
        __syncthreads();
    }
    if (t == 0) atomicAdd(out, red[0] * (1.0f / BB));
}

// Kernel 8: neg_pred = (||sum_b p_b||^2 - sum_b ||p_b||^2) / B
__global__ void negpred_kernel(const float* __restrict__ p, float* __restrict__ out) {
    int t = threadIdx.x;
    float u2 = 0.f, p2 = 0.f;
    for (int c = t; c < CC; c += 256) {
        float u = 0.f;
        for (int b = 0; b < BB; b++) {
            float v = p[b * CC + c];
            u += v;
            p2 += v * v;
        }
        u2 += u * u;
    }
    __shared__ float r1[256], r2[256];
    r1[t] = u2; r2[t] = p2;
    __syncthreads();
    for (int s = 128; s > 0; s >>= 1) {
        if (t < s) { r1[t] += r1[t + s]; r2[t] += r2[t + s]; }
        __syncthreads();
    }
    if (t == 0) atomicAdd(out, ALPHAC * (r1[0] - r2[0]) * (1.0f / BB));
}

extern "C" void kernel_launch(void* const* d_in, const int* in_sizes, int n_in,
                              void* d_out, int out_size, void* d_ws, size_t ws_size,
                              hipStream_t stream) {
    const float* feat  = (const float*)d_in[0];
    const float* pred  = (const float*)d_in[1];
    const float* bank  = (const float*)d_in[2];
    const float* sbank = (const float*)d_in[3];
    const int*   trg   = (const int*)d_in[4];
    float* out = (float*)d_out;

    char* ws = (char*)d_ws;
    float*          dist = (float*)ws;                          // 51,200,000 B
    float*          fn   = (float*)(ws + 51200000);             //    524,288 B
    unsigned short* fnb  = (unsigned short*)(ws + 51724288);    //    262,144 B
    float*          p    = (float*)(ws + 51986432);             //    353,280 B
    int*            win  = (int*)(ws + 52339712);               //      1,024 B
    int*            nidx = (int*)(ws + 52340736);               //      5,120 B

    winner_kernel<<<1, 256, 0, stream>>>(trg, win, out);
    norm_kernel<<<BB, 256, 0, stream>>>(feat, fn, fnb);
    softmax_kernel<<<BB, 256, 0, stream>>>(pred, p);
    gemm_kernel<<<(NBANK + TN - 1) / TN, 256, 0, stream>>>(fnb, bank, dist);
    fixup_kernel<<<BB, 256, 0, stream>>>(fn, trg, win, dist);
    topk_kernel<<<BB, 256, 0, stream>>>(dist, nidx);
    kl_kernel<<<BB, 256, 0, stream>>>(p, sbank, nidx, trg, out);
    negpred_kernel<<<1, 256, 0, stream>>>(p, out);
}

// Round 2
// 376.360 us; speedup vs baseline: 1.0777x; 1.0777x over previous
//
#include <hip/hip_runtime.h>
#include <cstdint>

#define BB 256
#define DD 512
#define CC 345
#define NBANK 50000
#define KNEI 5
#define ALPHAC 1.0f
#define EPSN 1e-12f

#define TN 64
#define BK 64
#define LDA 72
#define LDB 72
#define NBLK 782            // ceil(50000/64)
#define CAND (NBLK * 6)     // 4692 candidates per row

typedef short short8 __attribute__((ext_vector_type(8)));
typedef float f32x4 __attribute__((ext_vector_type(4)));

__device__ inline uint32_t f2bf1(float x) {
    union { float f; uint32_t u; } v; v.f = x;
    return (v.u + 0x7FFFu + ((v.u >> 16) & 1u)) >> 16;
}

__device__ inline bool better(float v1, int i1, float v2, int i2) {
    return (v1 > v2) || (v1 == v2 && i1 < i2);
}

// Kernel 1: repl[j] = -1 for all bank rows
__global__ void repl_init_kernel(int* __restrict__ repl) {
    int idx = blockIdx.x * 256 + threadIdx.x;
    if (idx < NBANK) repl[idx] = -1;
}

// Kernel 2: zero out, last-write-wins winner flags, scatter repl[trg[b]] = b
__global__ void winner_kernel(const int* __restrict__ trg, int* __restrict__ repl,
                              float* __restrict__ out) {
    int t = threadIdx.x;
    if (t == 0) out[0] = 0.f;
    int mv = trg[t];
    int w = 1;
    for (int b2 = t + 1; b2 < BB; b2++)
        if (trg[b2] == mv) w = 0;   // a later row writes the same bank slot
    if (w) repl[mv] = t;
}

// Kernel 3: row L2-normalize features -> bf16
__global__ void norm_kernel(const float* __restrict__ feat,
                            unsigned short* __restrict__ fnb) {
    int b = blockIdx.x, t = threadIdx.x;
    float x0 = feat[b * DD + t];
    float x1 = feat[b * DD + t + 256];
    __shared__ float red[256];
    red[t] = x0 * x0 + x1 * x1;
    __syncthreads();
    for (int s = 128; s > 0; s >>= 1) {
        if (t < s) red[t] += red[t + s];
        __syncthreads();
    }
    float inv = 1.0f / fmaxf(sqrtf(red[0]), EPSN);
    fnb[b * DD + t] = (unsigned short)f2bf1(x0 * inv);
    fnb[b * DD + t + 256] = (unsigned short)f2bf1(x1 * inv);
}

// Kernel 4: row softmax of predictions
__global__ void softmax_kernel(const float* __restrict__ pred, float* __restrict__ p) {
    int b = blockIdx.x, t = threadIdx.x;
    float x0 = (t < CC) ? pred[b * CC + t] : -3.0e38f;
    float x1 = (t + 256 < CC) ? pred[b * CC + t + 256] : -3.0e38f;
    __shared__ float red[256];
    red[t] = fmaxf(x0, x1);
    __syncthreads();
    for (int s = 128; s > 0; s >>= 1) {
        if (t < s) red[t] = fmaxf(red[t], red[t + s]);
        __syncthreads();
    }
    float M = red[0];
    __syncthreads();
    float e0 = (t < CC) ? expf(x0 - M) : 0.f;
    float e1 = (t + 256 < CC) ? expf(x1 - M) : 0.f;
    red[t] = e0 + e1;
    __syncthreads();
    for (int s = 128; s > 0; s >>= 1) {
        if (t < s) red[t] += red[t + s];
        __syncthreads();
    }
    float inv = 1.0f / red[0];
    if (t < CC) p[b * CC + t] = e0 * inv;
    if (t + 256 < CC) p[b * CC + t + 256] = e1 * inv;
}

// Kernel 5: fused distance GEMM (bf16 MFMA, all 256 rows x 64 bank cols per
// block, scatter-patched B staging via repl) + per-block per-row top-6.
__global__ __launch_bounds__(256) void gemm_topk_kernel(
        const unsigned short* __restrict__ fnb, const float* __restrict__ bank,
        const int* __restrict__ repl, float* __restrict__ cv, int* __restrict__ ci) {
    __shared__ __align__(16) char smem[46080];
    unsigned short* As = (unsigned short*)smem;    // [256][LDA] = 36864 B
    unsigned short* Bs = As + BB * LDA;            // [64][LDB]  =  9216 B
    float* Ep = (float*)smem;                      // [128][65]  = 33280 B (aliased)

    int t = threadIdx.x;
    int j0 = blockIdx.x * TN;
    int w = t >> 6, lane = t & 63, quad = lane >> 4, l16 = lane & 15;

    // B staging assignment: 4 threads per bank row, fixed for all k-tiles
    int br = t >> 2, cq = t & 3;
    int bj = j0 + br;
    int rp = (bj < NBANK) ? repl[bj] : -2;   // -2 OOB, -1 from bank, >=0 from fnb[rp]

    f32x4 acc[4][4];
#pragma unroll
    for (int mt = 0; mt < 4; mt++)
#pragma unroll
        for (int nt = 0; nt < 4; nt++)
            acc[mt][nt] = (f32x4){0.f, 0.f, 0.f, 0.f};

    for (int kt = 0; kt < DD / BK; kt++) {
        int k0 = kt * BK;
        // stage A: thread t copies its own row chunk (64 bf16 = 128 B)
        {
            const uint4* src = (const uint4*)(fnb + t * DD + k0);
            uint4* dst = (uint4*)(As + t * LDA);
#pragma unroll
            for (int u = 0; u < 8; u++) dst[u] = src[u];
        }
        // stage B: 16 floats per thread; scattered rows come from fnb (bf16)
        {
            uint4 b0, b1;
            if (rp >= 0) {
                const uint4* s = (const uint4*)(fnb + (size_t)rp * DD + k0 + cq * 16);
                b0 = s[0]; b1 = s[1];
            } else if (rp == -1) {
                const f32x4* s = (const f32x4*)(bank + (size_t)bj * DD + k0 + cq * 16);
                f32x4 f0 = s[0], f1 = s[1], f2 = s[2], f3 = s[3];
                b0 = make_uint4(f2bf1(f0[0]) | (f2bf1(f0[1]) << 16),
                                f2bf1(f0[2]) | (f2bf1(f0[3]) << 16),
                                f2bf1(f1[0]) | (f2bf1(f1[1]) << 16),
                                f2bf1(f1[2]) | (f2bf1(f1[3]) << 16));
                b1 = make_uint4(f2bf1(f2[0]) | (f2bf1(f2[1]) << 16),
                                f2bf1(f2[2]) | (f2bf1(f2[3]) << 16),
                                f2bf1(f3[0]) | (f2bf1(f3[1]) << 16),
                                f2bf1(f3[2]) | (f2bf1(f3[3]) << 16));
            } else {
                b0 = make_uint4(0, 0, 0, 0);
                b1 = make_uint4(0, 0, 0, 0);
            }
            uint4* dst = (uint4*)(Bs + br * LDB + cq * 16);
            dst[0] = b0; dst[1] = b1;
        }
        __syncthreads();
#pragma unroll
        for (int ks = 0; ks < 2; ks++) {
            short8 af[4], bf[4];
#pragma unroll
            for (int mt = 0; mt < 4; mt++)
                af[mt] = *(const short8*)(As + (w * 64 + mt * 16 + l16) * LDA + ks * 32 + quad * 8);
#pragma unroll
            for (int nt = 0; nt < 4; nt++)
                bf[nt] = *(const short8*)(Bs + (nt * 16 + l16) * LDB + ks * 32 + quad * 8);
#pragma unroll
            for (int mt = 0; mt < 4; mt++)
#pragma unroll
                for (int nt = 0; nt < 4; nt++)
                    acc[mt][nt] = __builtin_amdgcn_mfma_f32_16x16x32_bf16(
                        af[mt], bf[nt], acc[mt][nt], 0, 0, 0);
        }
        __syncthreads();
    }

    // Epilogue: two halves (128 rows each) through padded LDS, then top-6 scan.
#pragma unroll
    for (int half = 0; half < 2; half++) {
        if ((w >> 1) == half) {
            int wr = w & 1;
#pragma unroll
            for (int mt = 0; mt < 4; mt++)
#pragma unroll
                for (int nt = 0; nt < 4; nt++)
#pragma unroll
                    for (int r = 0; r < 4; r++)
                        Ep[(wr * 64 + mt * 16 + quad * 4 + r) * 65 + nt * 16 + l16] =
                            acc[mt][nt][r];
        }
        __syncthreads();
        if (t < 128) {
            int i = half * 128 + t;    // global feature row
            float lv[6]; int li[6];
#pragma unroll
            for (int r = 0; r < 6; r++) { lv[r] = -3.4e38f; li[r] = 0x7FFFFFFF; }
            for (int c = 0; c < TN; c++) {
                int j = j0 + c;
                float v = (j < NBANK) ? Ep[t * 65 + c] : -3.4e38f;
                if (better(v, j, lv[5], li[5])) {
                    int q = 5;
                    while (q > 0 && better(v, j, lv[q - 1], li[q - 1])) {
                        lv[q] = lv[q - 1]; li[q] = li[q - 1]; q--;
                    }
                    lv[q] = v; li[q] = j;
                }
            }
            size_t base = (size_t)i * CAND + (size_t)blockIdx.x * 6;
#pragma unroll
            for (int r = 0; r < 6; r++) { cv[base + r] = lv[r]; ci[base + r] = li[r]; }
        }
        __syncthreads();
    }
}

// Kernel 6: merge per-block candidates -> global top-6, keep ranks 1..5
__global__ void merge_kernel(const float* __restrict__ cv, const int* __restrict__ ci,
                             int* __restrict__ nidx) {
    int i = blockIdx.x, t = threadIdx.x;
    const float* rv = cv + (size_t)i * CAND;
    const int* ri = ci + (size_t)i * CAND;
    float lv[6]; int li[6];
#pragma unroll
    for (int r = 0; r < 6; r++) { lv[r] = -3.4e38f; li[r] = 0x7FFFFFFF; }
    for (int q = t; q < CAND; q += 256) {
        float v = rv[q]; int j = ri[q];
        if (better(v, j, lv[5], li[5])) {
            int s = 5;
            while (s > 0 && better(v, j, lv[s - 1], li[s - 1])) {
                lv[s] = lv[s - 1]; li[s] = li[s - 1]; s--;
            }
            lv[s] = v; li[s] = j;
        }
    }
    __shared__ float sv[1536];
    __shared__ int si[1536];
#pragma unroll
    for (int r = 0; r < 6; r++) { sv[t * 6 + r] = lv[r]; si[t * 6 + r] = li[r]; }
    __syncthreads();
    for (int s = 128; s > 0; s >>= 1) {
        if (t < s) {
            float av[6], bv[6], rvv[6];
            int ai[6], bi[6], rii[6];
#pragma unroll
            for (int r = 0; r < 6; r++) {
                av[r] = sv[t * 6 + r];       ai[r] = si[t * 6 + r];
                bv[r] = sv[(t + s) * 6 + r]; bi[r] = si[(t + s) * 6 + r];
            }
            int x = 0, y = 0;
#pragma unroll
            for (int o = 0; o < 6; o++) {
                if (better(av[x], ai[x], bv[y], bi[y])) { rvv[o] = av[x]; rii[o] = ai[x]; x++; }
                else                                    { rvv[o] = bv[y]; rii[o] = bi[y]; y++; }
            }
#pragma unroll
            for (int r = 0; r < 6; r++) { sv[t * 6 + r] = rvv[r]; si[t * 6 + r] = rii[r]; }
        }
        __syncthreads();
    }
    if (t == 0) {
#pragma unroll
        for (int r = 1; r < 6; r++) nidx[i * KNEI + r - 1] = si[r];
    }
}

// Kernel 7: KL term, gathering score rows with scatter patch (last-wins lookup)
__global__ void kl_kernel(const float* __restrict__ p, const float* __restrict__ sbank,
                          const int* __restrict__ nidx, const int* __restrict__ trg,
                          float* __restrict__ out) {
    int b = blockIdx.x, t = threadIdx.x;
    __shared__ int sj[KNEI], sb[KNEI];
    if (t < KNEI) {
        int j = nidx[b * KNEI + t];
        sj[t] = j;
        int src = -1;
        for (int b2 = 0; b2 < BB; b2++)
            if (trg[b2] == j) src = b2;   // last wins
        sb[t] = src;
    }
    __syncthreads();
    float local = 0.f;
    for (int k = 0; k < KNEI; k++) {
        int j = sj[k], src = sb[k];
        const float* srow = (src >= 0) ? (p + src * CC) : (sbank + (size_t)j * CC);
        for (int c = t; c < CC; c += 256) {
            float s = srow[c];
            local += s * (logf(s) - p[b * CC + c]);
        }
    }
    __shared__ float red[256];
    red[t] = local;
    __syncthreads();
    for (int s = 128; s > 0; s >>= 1) {
        if (t < s) red[t] += red[t + s];
        __syncthreads();
    }
    if (t == 0) atomicAdd(out, red[0] * (1.0f / BB));
}

// Kernel 8: neg_pred = (||sum_b p_b||^2 - sum_b ||p_b||^2) / B  (col-owning threads)
__global__ void negpred_kernel(const float* __restrict__ p, float* __restrict__ out) {
    int t = threadIdx.x;   // 512 threads, col c = t
    float colsum = 0.f, p2 = 0.f;
    if (t < CC) {
        for (int b = 0; b < BB; b++) {
            float v = p[b * CC + t];
            colsum += v;
            p2 += v * v;
        }
    }
    __shared__ float r1[512], r2[512];
    r1[t] = colsum * colsum;
    r2[t] = p2;
    __syncthreads();
    for (int s = 256; s > 0; s >>= 1) {
        if (t < s) { r1[t] += r1[t + s]; r2[t] += r2[t + s]; }
        __syncthreads();
    }
    if (t == 0) atomicAdd(out, ALPHAC * (r1[0] - r2[0]) * (1.0f / BB));
}

extern "C" void kernel_launch(void* const* d_in, const int* in_sizes, int n_in,
                              void* d_out, int out_size, void* d_ws, size_t ws_size,
                              hipStream_t stream) {
    const float* feat  = (const float*)d_in[0];
    const float* pred  = (const float*)d_in[1];
    const float* bank  = (const float*)d_in[2];
    const float* sbank = (const float*)d_in[3];
    const int*   trg   = (const int*)d_in[4];
    float* out = (float*)d_out;

    char* ws = (char*)d_ws;
    float*          cv   = (float*)ws;                          // 4,804,608 B
    int*            ci   = (int*)(ws + 4804608);                // 4,804,608 B
    unsigned short* fnb  = (unsigned short*)(ws + 9609216);     //   262,144 B
    float*          p    = (float*)(ws + 9871360);              //   353,280 B
    int*            repl = (int*)(ws + 10224640);               //   200,192 B
    int*            nidx = (int*)(ws + 10424832);               //     5,120 B

    repl_init_kernel<<<(NBANK + 255) / 256, 256, 0, stream>>>(repl);
    winner_kernel<<<1, 256, 0, stream>>>(trg, repl, out);
    norm_kernel<<<BB, 256, 0, stream>>>(feat, fnb);
    softmax_kernel<<<BB, 256, 0, stream>>>(pred, p);
    gemm_topk_kernel<<<NBLK, 256, 0, stream>>>(fnb, bank, repl, cv, ci);
    merge_kernel<<<BB, 256, 0, stream>>>(cv, ci, nidx);
    kl_kernel<<<BB, 256, 0, stream>>>(p, sbank, nidx, trg, out);
    negpred_kernel<<<1, 512, 0, stream>>>(p, out);
}